// Round 13
// baseline (881.290 us; speedup 1.0000x reference)
//
#include <hip/hip_runtime.h>
#include <hip/hip_bf16.h>

#define IN_DIM 1024
#define H_DIM  1024
#define C_DIM  16
#define B_DIM  4096
#define K_DIM  2048      // IN + H
#define N_DIM  32768     // C * 2H
#define M_DIM  4096      // B
#define NT     64        // K_DIM / 32 K-steps

typedef __attribute__((ext_vector_type(8))) short short8;
typedef __attribute__((ext_vector_type(4))) float f32x4;

__device__ __forceinline__ unsigned short f2bf_rne(float f) {
  union { float f; unsigned u; } a; a.f = f;
  unsigned r = a.u + 0x7FFFu + ((a.u >> 16) & 1u);
  return (unsigned short)(r >> 16);
}

// Pack rows: out[r][0:1024] = bf16(xs[r][:]), out[r][1024:2048] = bf16(hs[r][:])
__global__ void convert_pack_kernel(const float* __restrict__ xs,
                                    const float* __restrict__ hs,
                                    unsigned short* __restrict__ out,
                                    int rows) {
  long total = (long)rows * (K_DIM / 8);
  for (long i = blockIdx.x * (long)blockDim.x + threadIdx.x; i < total;
       i += (long)gridDim.x * blockDim.x) {
    long e = i * 8;
    int r = (int)(e >> 11);
    int k = (int)(e & 2047);
    const float* src = (k < IN_DIM) ? (xs + (long)r * IN_DIM + k)
                                    : (hs + (long)r * H_DIM + (k - IN_DIM));
    float4 v0 = *(const float4*)(src);
    float4 v1 = *(const float4*)(src + 4);
    union { unsigned short u[8]; short8 s; } p;
    p.u[0] = f2bf_rne(v0.x); p.u[1] = f2bf_rne(v0.y);
    p.u[2] = f2bf_rne(v0.z); p.u[3] = f2bf_rne(v0.w);
    p.u[4] = f2bf_rne(v1.x); p.u[5] = f2bf_rne(v1.y);
    p.u[6] = f2bf_rne(v1.z); p.u[7] = f2bf_rne(v1.w);
    *(short8*)(out + e) = p.s;
  }
}

__device__ __forceinline__ void gl16(const short* g, short* l) {
  __builtin_amdgcn_global_load_lds(
      (const __attribute__((address_space(1))) unsigned int*)g,
      (__attribute__((address_space(3))) unsigned int*)l, 16, 0, 0);
}

// C = A(M x K) * Bt(N x K)^T + bias, fused sigmoid/tanh epilogue.
// ROUND 13 — m97 structure (the proven 874-912 TF plain-HIP point), with
// the two round-1 defects fixed:
//   * geometry: 128x128 tile, BK=32, 4 waves (2x2), wave tile 64x64,
//     SINGLE-buffered 32 KiB LDS (A 8KB + B 8KB... x1 buf), 2 syncs/step.
//     -> 4 blocks/CU co-resident (__launch_bounds__(256,4)); cross-BLOCK
//     TLP provides MFMA/mem overlap (m114); no common barrier across blocks.
//     Eight 1-block/CU schedule variants (rounds 2-12) all pinned at
//     27-33% MfmaUtil; this moves the occupancy axis instead.
//   * BK=32 bank swizzle: 64B rows -> granule(r,c) = (4r + c) mod 8, so
//     chunk c must be XORed with (r>>1)&3 (NOT r&7, which only works for
//     128B rows). Each 8-lane group then covers all 8 granules once.
//     Staging pre-swizzles the GLOBAL chunk (involution; rows 64+ use the
//     same XOR since (64+r)>>1 == r>>1 mod 4). Round-1's 6.7e7 conflicts -> ~0.
//   * NT-store epilogue + hoisted bias (FETCH 1.3 GB -> ~0.7 GB, round 2).
__global__ void __launch_bounds__(256, 4)
gemm_act_kernel(const short* __restrict__ A,   // [M][K] bf16 bits
                const short* __restrict__ Bt,  // [N][K] bf16 bits
                const float* __restrict__ bias,// [N]
                float* __restrict__ out) {
  __shared__ short lA[128 * 32];   // 8 KiB
  __shared__ short lB[128 * 32];   // 8 KiB

  // bijective XCD swizzle (nwg = 8192, divisible by 8); m-fastest tiling
  int cpx = (int)gridDim.x >> 3;
  int wg  = ((int)blockIdx.x & 7) * cpx + ((int)blockIdx.x >> 3);
  int mt = wg & 31;            // M/128 = 32 tiles (fast: share B panel in L2)
  int nt = wg >> 5;            // N/128 = 256 tiles
  int m0 = mt * 128;
  int n0 = nt * 128;

  const int tid  = (int)threadIdx.x;
  const int lane = tid & 63;
  const int wid  = tid >> 6;
  const int wr   = (wid >> 1) * 64;   // wave row offset in tile
  const int wc   = (wid & 1) * 64;    // wave col offset in tile

  // ---- epilogue constants (hoisted before any DMA) ----
  const int crow = (lane >> 4) * 4;
  const int ccol = lane & 15;
  const long HALF = (long)B_DIM * C_DIM * H_DIM;  // 67108864
  float bia[4]; int cg[4], og[4];
#pragma unroll
  for (int ni = 0; ni < 4; ++ni) {
    int gn = n0 + wc + ni * 16 + ccol;
    bia[ni] = bias[gn];
    cg[ni] = gn >> 11;
    og[ni] = gn & 2047;
  }

  // ---- staging: thread t -> LDS row srow = t>>2, chunk sg = t&3 (lane-
  // linear dest = t*16 bytes). Global source chunk pre-swizzled. ----
  const int srow = tid >> 2;                       // 0..63
  const int sg   = tid & 3;
  const int sgg  = sg ^ ((srow >> 1) & 3);         // swizzled source chunk
  const short* Asrc = A  + (long)(m0 + srow) * K_DIM + sgg * 8;
  const short* Bsrc = Bt + (long)(n0 + srow) * K_DIM + sgg * 8;
  const int dOff = srow * 32 + sg * 8;             // shorts; rows 64+: +2048

  // ---- fragment read offsets: row r, k-chunk g8 -> LDS chunk g8^((r>>1)&3)
  const int fr = lane & 15;
  const int g8 = lane >> 4;
  int aoff[4], boff[4];
#pragma unroll
  for (int i = 0; i < 4; ++i) {
    int ra = wr + i * 16 + fr;
    int rb = wc + i * 16 + fr;
    aoff[i] = ra * 32 + ((g8 ^ ((ra >> 1) & 3)) << 3);
    boff[i] = rb * 32 + ((g8 ^ ((rb >> 1) & 3)) << 3);
  }

  f32x4 acc[4][4] = {};

  for (int t = 0; t < NT; ++t) {
    // stage K-step t (A: 2 quarters, B: 2 quarters)
    const int ko = t * 32;
    gl16(Asrc + ko,                    lA + dOff);
    gl16(Asrc + (long)64 * K_DIM + ko, lA + 2048 + dOff);
    gl16(Bsrc + ko,                    lB + dOff);
    gl16(Bsrc + (long)64 * K_DIM + ko, lB + 2048 + dOff);
    __syncthreads();   // drains DMA (vmcnt 0) for all waves

    short8 av[4], bv[4];
#pragma unroll
    for (int i = 0; i < 4; ++i) av[i] = *(const short8*)(lA + aoff[i]);
#pragma unroll
    for (int i = 0; i < 4; ++i) bv[i] = *(const short8*)(lB + boff[i]);
#pragma unroll
    for (int mi = 0; mi < 4; ++mi)
#pragma unroll
      for (int ni = 0; ni < 4; ++ni)
        acc[mi][ni] = __builtin_amdgcn_mfma_f32_16x16x32_bf16(av[mi], bv[ni], acc[mi][ni], 0, 0, 0);
    __syncthreads();   // reads complete before next step's overwrite
  }

  // ---- epilogue: C/D layout col=lane&15, row=(lane>>4)*4+j ----
#pragma unroll
  for (int mi = 0; mi < 4; ++mi) {
    int gb0 = m0 + wr + mi * 16 + crow;
#pragma unroll
    for (int ni = 0; ni < 4; ++ni) {
      int c = cg[ni], o = og[ni];
#pragma unroll
      for (int j = 0; j < 4; ++j) {
        float v = acc[mi][ni][j] + bia[ni];
        long b = gb0 + j;
        if (o < H_DIM) {  // input_gate = sigmoid -> output 1 (second half)
          float r = 1.0f / (1.0f + __expf(-v));
          __builtin_nontemporal_store(r, &out[HALF + (b * C_DIM + c) * H_DIM + o]);
        } else {          // cell_input = tanh -> output 0 (first half)
          float av2 = fabsf(v);
          float e = __expf(-2.0f * av2);
          float r = (1.0f - e) / (1.0f + e);
          r = (v < 0.0f) ? -r : r;
          __builtin_nontemporal_store(r, &out[(b * C_DIM + c) * H_DIM + (o - H_DIM)]);
        }
      }
    }
  }
}

// Correctness-only fallback if workspace is too small for bf16 staging.
__global__ void fallback_kernel(const float* __restrict__ x,
                                const float* __restrict__ h,
                                const float* __restrict__ Wx,
                                const float* __restrict__ bx,
                                const float* __restrict__ Wh,
                                float* __restrict__ out) {
  int b = blockIdx.x;
  int c = blockIdx.y;
  __shared__ float lx[IN_DIM], lh[H_DIM];
  for (int i = threadIdx.x; i < IN_DIM; i += blockDim.x) {
    lx[i] = x[(long)b * IN_DIM + i];
    lh[i] = h[(long)b * H_DIM + i];
  }
  __syncthreads();
  const long HALF = (long)B_DIM * C_DIM * H_DIM;
  for (int o = threadIdx.x; o < 2 * H_DIM; o += blockDim.x) {
    const float* wx = Wx + ((long)c * 2 * H_DIM + o) * IN_DIM;
    const float* wh = Wh + ((long)c * 2 * H_DIM + o) * H_DIM;
    float acc = bx[c * 2 * H_DIM + o];
    for (int k = 0; k < IN_DIM; ++k) acc += lx[k] * wx[k];
    for (int k = 0; k < H_DIM; ++k) acc += lh[k] * wh[k];
    if (o < H_DIM) {
      out[HALF + ((long)b * C_DIM + c) * H_DIM + o] = 1.0f / (1.0f + __expf(-acc));
    } else {
      float av = fabsf(acc);
      float t = __expf(-2.0f * av);
      float r = (1.0f - t) / (1.0f + t);
      out[((long)b * C_DIM + c) * H_DIM + (o - H_DIM)] = (acc < 0.0f) ? -r : r;
    }
  }
}

extern "C" void kernel_launch(void* const* d_in, const int* in_sizes, int n_in,
                              void* d_out, int out_size, void* d_ws, size_t ws_size,
                              hipStream_t stream) {
  const float* x  = (const float*)d_in[0];   // (B, IN)
  const float* h  = (const float*)d_in[1];   // (B, H)
  const float* Wx = (const float*)d_in[2];   // (C, 2H, IN)
  const float* bx = (const float*)d_in[3];   // (C, 2H)
  const float* Wh = (const float*)d_in[4];   // (C, 2H, H)
  float* out = (float*)d_out;                // [cell_input | input_gate], each (B,C,H)

  const size_t needA = (size_t)M_DIM * K_DIM * sizeof(short);  // 16 MiB
  const size_t needB = (size_t)N_DIM * K_DIM * sizeof(short);  // 128 MiB
  if (ws_size < needA + needB) {
    dim3 g(B_DIM, C_DIM);
    fallback_kernel<<<g, 256, 0, stream>>>(x, h, Wx, bx, Wh, out);
    return;
  }

  unsigned short* Abf = (unsigned short*)d_ws;
  unsigned short* Bbf = (unsigned short*)((char*)d_ws + needA);

  convert_pack_kernel<<<2048, 256, 0, stream>>>(x, h, Abf, M_DIM);
  convert_pack_kernel<<<4096, 256, 0, stream>>>(Wx, Wh, Bbf, N_DIM);

  gemm_act_kernel<<<8192, 256, 0, stream>>>((const short*)Abf, (const short*)Bbf,
                                            bx, out);
}

// Round 14
// 817.657 us; speedup vs baseline: 1.0778x; 1.0778x over previous
//
#include <hip/hip_runtime.h>
#include <hip/hip_bf16.h>

#define IN_DIM 1024
#define H_DIM  1024
#define C_DIM  16
#define B_DIM  4096
#define K_DIM  2048      // IN + H
#define N_DIM  32768     // C * 2H
#define M_DIM  4096      // B
#define NT     32        // K_DIM / 64 K-steps

typedef __attribute__((ext_vector_type(8))) short short8;
typedef __attribute__((ext_vector_type(4))) float f32x4;

__device__ __forceinline__ unsigned short f2bf_rne(float f) {
  union { float f; unsigned u; } a; a.f = f;
  unsigned r = a.u + 0x7FFFu + ((a.u >> 16) & 1u);
  return (unsigned short)(r >> 16);
}

// Pack rows: out[r][0:1024] = bf16(xs[r][:]), out[r][1024:2048] = bf16(hs[r][:])
__global__ void convert_pack_kernel(const float* __restrict__ xs,
                                    const float* __restrict__ hs,
                                    unsigned short* __restrict__ out,
                                    int rows) {
  long total = (long)rows * (K_DIM / 8);
  for (long i = blockIdx.x * (long)blockDim.x + threadIdx.x; i < total;
       i += (long)gridDim.x * blockDim.x) {
    long e = i * 8;
    int r = (int)(e >> 11);
    int k = (int)(e & 2047);
    const float* src = (k < IN_DIM) ? (xs + (long)r * IN_DIM + k)
                                    : (hs + (long)r * H_DIM + (k - IN_DIM));
    float4 v0 = *(const float4*)(src);
    float4 v1 = *(const float4*)(src + 4);
    union { unsigned short u[8]; short8 s; } p;
    p.u[0] = f2bf_rne(v0.x); p.u[1] = f2bf_rne(v0.y);
    p.u[2] = f2bf_rne(v0.z); p.u[3] = f2bf_rne(v0.w);
    p.u[4] = f2bf_rne(v1.x); p.u[5] = f2bf_rne(v1.y);
    p.u[6] = f2bf_rne(v1.z); p.u[7] = f2bf_rne(v1.w);
    *(short8*)(out + e) = p.s;
  }
}

__device__ __forceinline__ void gl16(const short* g, short* l) {
  __builtin_amdgcn_global_load_lds(
      (const __attribute__((address_space(1))) unsigned int*)g,
      (__attribute__((address_space(3))) unsigned int*)l, 16, 0, 0);
}

// Opaque ds_read: un-sinkable, un-rematerializable. Forces the pre-barrier
// issue slot and the register liveness the schedule requires. (Round-13
// post-mortem: VGPR_Count=108-116 proved hipcc was sinking IR ds_reads to
// just before each MFMA use, serializing LDS latency into the MFMA region
// across all nine prior source schedules.)
__device__ __forceinline__ short8 ldsr16(unsigned addr) {
  short8 r;
  asm volatile("ds_read_b128 %0, %1" : "=v"(r) : "v"(addr));
  return r;
}

// C = A(M x K) * Bt(N x K)^T + bias, fused sigmoid/tanh epilogue.
// Round-10 kernel (verified slots/ledger) + rule-18 read discipline:
// per phase: { asm ds_reads (pre-barrier); stage (builtin DMA);
//   [vmcnt(4) @ph3/ph7, "memory"]; s_barrier;
//   s_waitcnt lgkmcnt(0); sched_barrier(0);    <- rule 18
//   setprio(1); 16 MFMA; setprio(0); s_barrier; }
// Quarter grouping (round-9 verified): A-lo (mi0-3) = {q0,q128};
// A-hi (mi4-7) = {q64,q192} — no phase stages a quarter it reads.
// FIFO: entry=4, peak=12; end-ph3 vmcnt(4) retires all of t1 (read ph4-7);
// end-ph7 vmcnt(4) retires all of t2 (read next ph0-3). Never drained.
__global__ void __launch_bounds__(512, 2)
gemm_act_kernel(const short* __restrict__ A,   // [M][K] bf16 bits
                const short* __restrict__ Bt,  // [N][K] bf16 bits
                const float* __restrict__ bias,// [N]
                float* __restrict__ out) {
  extern __shared__ short lds[];
  // byte bases (dynamic LDS starts at 0): A0=0, A1=32768, B0=65536, B1=98304

  // bijective XCD swizzle (nwg = 2048, divisible by 8); m-fastest tiling
  int cpx = (int)gridDim.x >> 3;
  int wg  = ((int)blockIdx.x & 7) * cpx + ((int)blockIdx.x >> 3);
  int mt = wg & 15;           // M/256 = 16 tiles
  int nt = wg >> 4;           // N/256 = 128 tiles
  int m0 = mt * 256;
  int n0 = nt * 256;

  const int tid  = (int)threadIdx.x;
  const int lane = tid & 63;
  const int wid  = tid >> 6;
  const int wr   = wid >> 2;   // wave rows wr*128
  const int wc   = wid & 3;    // wave cols wc*64

  // ---- epilogue constants FIRST (only IR vmem loads, before any DMA) ----
  const int crow = (lane >> 4) * 4;
  const int ccol = lane & 15;
  const long HALF = (long)B_DIM * C_DIM * H_DIM;  // 67108864
  float bia[4]; int cg[4], og[4];
#pragma unroll
  for (int ni = 0; ni < 4; ++ni) {
    int gn = n0 + wc * 64 + ni * 16 + ccol;
    bia[ni] = bias[gn];
    cg[ni] = gn >> 11;
    og[ni] = gn & 2047;
  }

  // ---- staging (T2: swizzled global source, lane-linear LDS dest) ----
  const int srow = tid >> 3;                 // 0..63 row within quarter
  const int sc   = (tid & 7) ^ (srow & 7);   // swizzled src 16B chunk
  const short* Abase = A  + (long)(m0 + srow) * K_DIM + sc * 8;
  const short* Bbase = Bt + (long)(n0 + srow) * K_DIM + sc * 8;
  const int dstT = tid * 8;                  // per-thread dest (shorts)

  auto stA = [&](int kt, int r0, int bufS) {   // one 64-row quarter
    gl16(Abase + (long)r0 * K_DIM + kt * 64, lds + bufS + r0 * 64 + dstT);
  };
  auto stB = [&](int kt, int r0, int bufS) {
    gl16(Bbase + (long)r0 * K_DIM + kt * 64, lds + 32768 + bufS + r0 * 64 + dstT);
  };

  // ---- fragment LDS BYTE offsets; mi adds mi*2048 bytes ----
  const int fr = lane & 15;
  const int g8 = lane >> 4;
  unsigned aoffB[2], boffB[2];
#pragma unroll
  for (int kk = 0; kk < 2; ++kk) {
    aoffB[kk] = 2u * ((wr * 128 + fr) * 64 + (((kk * 4 + g8) ^ (fr & 7)) << 3));
    boffB[kk] = 2u * ((wc * 64  + fr) * 64 + (((kk * 4 + g8) ^ (fr & 7)) << 3));
  }

  f32x4 acc[8][4] = {};
  auto mfma4 = [&](short8 (&a)[4], short8 (&b)[4], int mb) {
#pragma unroll
    for (int i = 0; i < 4; ++i)
#pragma unroll
      for (int j = 0; j < 4; ++j)
        acc[mb + i][j] = __builtin_amdgcn_mfma_f32_16x16x32_bf16(a[i], b[j], acc[mb + i][j], 0, 0, 0);
  };

  // rule-18 gate: all reads retired, nothing crosses this point
  #define LGKM_GATE() do {                                         \
    asm volatile("s_waitcnt lgkmcnt(0)" ::: "memory");             \
    __builtin_amdgcn_sched_barrier(0);                             \
  } while (0)

  // ---- prologue: tile0 full (8 loads) + {A-lo{q0,q128}, B-h0}(1) ----
  stA(0, 0, 0);      stA(0, 64, 0);      stA(0, 128, 0);      stA(0, 192, 0);
  stB(0, 0, 0);      stB(0, 64, 0);      stB(0, 128, 0);      stB(0, 192, 0);
  stA(1, 0, 16384);  stA(1, 128, 16384);
  stB(1, 0, 16384);  stB(1, 64, 16384);
  asm volatile("s_waitcnt vmcnt(4)" ::: "memory");  // retires tile0; 4 in flight
  __builtin_amdgcn_s_barrier();

  for (int t = 0; t < NT; t += 2) {
    const int t1 = t + 1;                         // always < NT
    const int t2 = (t + 2 < NT) ? t + 2 : NT - 1; // clamped tail: rewrites
    const int t3 = (t + 3 < NT) ? t + 3 : NT - 1; // identical bytes (safe)
    short8 av[4], bv0[4], bv1[4];
    // ---- ph0: reads A0.lo.k0 + B0.k0; stage A-hi{q64,q192}+B-h1(t1)->buf1 --
#pragma unroll
    for (int i = 0; i < 4; ++i) av[i] = ldsr16(0u + aoffB[0] + i * 2048);
#pragma unroll
    for (int j = 0; j < 4; ++j) bv0[j] = ldsr16(65536u + boffB[0] + j * 2048);
    stA(t1, 64, 16384); stA(t1, 192, 16384);
    stB(t1, 128, 16384); stB(t1, 192, 16384);
    __builtin_amdgcn_s_barrier();
    LGKM_GATE();
    __builtin_amdgcn_s_setprio(1);
    mfma4(av, bv0, 0);
    __builtin_amdgcn_s_setprio(0);
    __builtin_amdgcn_s_barrier();
    // ---- ph1: reads A0.lo.k1 + B0.k1; no stage ----
#pragma unroll
    for (int i = 0; i < 4; ++i) av[i] = ldsr16(0u + aoffB[1] + i * 2048);
#pragma unroll
    for (int j = 0; j < 4; ++j) bv1[j] = ldsr16(65536u + boffB[1] + j * 2048);
    __builtin_amdgcn_s_barrier();
    LGKM_GATE();
    __builtin_amdgcn_s_setprio(1);
    mfma4(av, bv1, 0);
    __builtin_amdgcn_s_setprio(0);
    __builtin_amdgcn_s_barrier();
    // ---- ph2: reads A0.hi.k0 {q64,q192}; stage A-lo{q0,q128}(t2)->buf0 ----
#pragma unroll
    for (int i = 0; i < 4; ++i) av[i] = ldsr16(0u + aoffB[0] + (4 + i) * 2048);
    stA(t2, 0, 0); stA(t2, 128, 0);
    __builtin_amdgcn_s_barrier();
    LGKM_GATE();
    __builtin_amdgcn_s_setprio(1);
    mfma4(av, bv0, 4);
    __builtin_amdgcn_s_setprio(0);
    __builtin_amdgcn_s_barrier();
    // ---- ph3: reads A0.hi.k1; stage B-h0(t2)->buf0; vmcnt(4) ----
#pragma unroll
    for (int i = 0; i < 4; ++i) av[i] = ldsr16(0u + aoffB[1] + (4 + i) * 2048);
    stB(t2, 0, 0); stB(t2, 64, 0);
    asm volatile("s_waitcnt vmcnt(4)" ::: "memory");  // retires all of t1
    __builtin_amdgcn_s_barrier();
    LGKM_GATE();
    __builtin_amdgcn_s_setprio(1);
    mfma4(av, bv1, 4);
    __builtin_amdgcn_s_setprio(0);
    __builtin_amdgcn_s_barrier();
    // ---- ph4: reads A1.lo.k0 + B1.k0; stage A-hi{q64,q192}+B-h1(t2)->buf0 --
#pragma unroll
    for (int i = 0; i < 4; ++i) av[i] = ldsr16(32768u + aoffB[0] + i * 2048);
#pragma unroll
    for (int j = 0; j < 4; ++j) bv0[j] = ldsr16(98304u + boffB[0] + j * 2048);
    stA(t2, 64, 0); stA(t2, 192, 0);
    stB(t2, 128, 0); stB(t2, 192, 0);
    __builtin_amdgcn_s_barrier();
    LGKM_GATE();
    __builtin_amdgcn_s_setprio(1);
    mfma4(av, bv0, 0);
    __builtin_amdgcn_s_setprio(0);
    __builtin_amdgcn_s_barrier();
    // ---- ph5: reads A1.lo.k1 + B1.k1; no stage ----
#pragma unroll
    for (int i = 0; i < 4; ++i) av[i] = ldsr16(32768u + aoffB[1] + i * 2048);
#pragma unroll
    for (int j = 0; j < 4; ++j) bv1[j] = ldsr16(98304u + boffB[1] + j * 2048);
    __builtin_amdgcn_s_barrier();
    LGKM_GATE();
    __builtin_amdgcn_s_setprio(1);
    mfma4(av, bv1, 0);
    __builtin_amdgcn_s_setprio(0);
    __builtin_amdgcn_s_barrier();
    // ---- ph6: reads A1.hi.k0 {q64,q192}; stage A-lo{q0,q128}(t3)->buf1 ----
#pragma unroll
    for (int i = 0; i < 4; ++i) av[i] = ldsr16(32768u + aoffB[0] + (4 + i) * 2048);
    stA(t3, 0, 16384); stA(t3, 128, 16384);
    __builtin_amdgcn_s_barrier();
    LGKM_GATE();
    __builtin_amdgcn_s_setprio(1);
    mfma4(av, bv0, 4);
    __builtin_amdgcn_s_setprio(0);
    __builtin_amdgcn_s_barrier();
    // ---- ph7: reads A1.hi.k1; stage B-h0(t3)->buf1; vmcnt(4) ----
#pragma unroll
    for (int i = 0; i < 4; ++i) av[i] = ldsr16(32768u + aoffB[1] + (4 + i) * 2048);
    stB(t3, 0, 16384); stB(t3, 64, 16384);
    asm volatile("s_waitcnt vmcnt(4)" ::: "memory");  // retires all of t2
    __builtin_amdgcn_s_barrier();
    LGKM_GATE();
    __builtin_amdgcn_s_setprio(1);
    mfma4(av, bv1, 4);
    __builtin_amdgcn_s_setprio(0);
    __builtin_amdgcn_s_barrier();
  }
  asm volatile("s_waitcnt vmcnt(0)" ::: "memory");

  // ---- epilogue: C/D layout col=lane&15, row=(lane>>4)*4+j ----
#pragma unroll
  for (int mi = 0; mi < 8; ++mi) {
    int gb0 = m0 + wr * 128 + mi * 16 + crow;
#pragma unroll
    for (int ni = 0; ni < 4; ++ni) {
      int c = cg[ni], o = og[ni];
#pragma unroll
      for (int j = 0; j < 4; ++j) {
        float v = acc[mi][ni][j] + bia[ni];
        long b = gb0 + j;
        if (o < H_DIM) {  // input_gate = sigmoid -> output 1 (second half)
          float r = 1.0f / (1.0f + __expf(-v));
          __builtin_nontemporal_store(r, &out[HALF + (b * C_DIM + c) * H_DIM + o]);
        } else {          // cell_input = tanh -> output 0 (first half)
          float av2 = fabsf(v);
          float e = __expf(-2.0f * av2);
          float r = (1.0f - e) / (1.0f + e);
          r = (v < 0.0f) ? -r : r;
          __builtin_nontemporal_store(r, &out[(b * C_DIM + c) * H_DIM + (o - H_DIM)]);
        }
      }
    }
  }
  #undef LGKM_GATE
}

// Correctness-only fallback if workspace is too small for bf16 staging.
__global__ void fallback_kernel(const float* __restrict__ x,
                                const float* __restrict__ h,
                                const float* __restrict__ Wx,
                                const float* __restrict__ bx,
                                const float* __restrict__ Wh,
                                float* __restrict__ out) {
  int b = blockIdx.x;
  int c = blockIdx.y;
  __shared__ float lx[IN_DIM], lh[H_DIM];
  for (int i = threadIdx.x; i < IN_DIM; i += blockDim.x) {
    lx[i] = x[(long)b * IN_DIM + i];
    lh[i] = h[(long)b * H_DIM + i];
  }
  __syncthreads();
  const long HALF = (long)B_DIM * C_DIM * H_DIM;
  for (int o = threadIdx.x; o < 2 * H_DIM; o += blockDim.x) {
    const float* wx = Wx + ((long)c * 2 * H_DIM + o) * IN_DIM;
    const float* wh = Wh + ((long)c * 2 * H_DIM + o) * H_DIM;
    float acc = bx[c * 2 * H_DIM + o];
    for (int k = 0; k < IN_DIM; ++k) acc += lx[k] * wx[k];
    for (int k = 0; k < H_DIM; ++k) acc += lh[k] * wh[k];
    if (o < H_DIM) {
      out[HALF + ((long)b * C_DIM + c) * H_DIM + o] = 1.0f / (1.0f + __expf(-acc));
    } else {
      float av = fabsf(acc);
      float t = __expf(-2.0f * av);
      float r = (1.0f - t) / (1.0f + t);
      out[((long)b * C_DIM + c) * H_DIM + (o - H_DIM)] = (acc < 0.0f) ? -r : r;
    }
  }
}

extern "C" void kernel_launch(void* const* d_in, const int* in_sizes, int n_in,
                              void* d_out, int out_size, void* d_ws, size_t ws_size,
                              hipStream_t stream) {
  const float* x  = (const float*)d_in[0];   // (B, IN)
  const float* h  = (const float*)d_in[1];   // (B, H)
  const float* Wx = (const float*)d_in[2];   // (C, 2H, IN)
  const float* bx = (const float*)d_in[3];   // (C, 2H)
  const float* Wh = (const float*)d_in[4];   // (C, 2H, H)
  float* out = (float*)d_out;                // [cell_input | input_gate], each (B,C,H)

  const size_t needA = (size_t)M_DIM * K_DIM * sizeof(short);  // 16 MiB
  const size_t needB = (size_t)N_DIM * K_DIM * sizeof(short);  // 128 MiB
  if (ws_size < needA + needB) {
    dim3 g(B_DIM, C_DIM);
    fallback_kernel<<<g, 256, 0, stream>>>(x, h, Wx, bx, Wh, out);
    return;
  }

  unsigned short* Abf = (unsigned short*)d_ws;
  unsigned short* Bbf = (unsigned short*)((char*)d_ws + needA);

  convert_pack_kernel<<<2048, 256, 0, stream>>>(x, h, Abf, M_DIM);
  convert_pack_kernel<<<4096, 256, 0, stream>>>(Wx, Wh, Bbf, N_DIM);

  (void)hipFuncSetAttribute((const void*)gemm_act_kernel,
                            hipFuncAttributeMaxDynamicSharedMemorySize, 131072);
  gemm_act_kernel<<<2048, 512, 131072, stream>>>((const short*)Abf, (const short*)Bbf,
                                                 bx, out);
}